// Round 5
// baseline (170.692 us; speedup 1.0000x reference)
//
#include <hip/hip_runtime.h>
#include <stdint.h>

#define GDIM   512
#define HID    150
#define HIDP   160    // HID padded to multiple of 16
#define NROWS  12000
#define KP1    31     // KMAX+1
#define BM     128    // pairs (or rows) per block
#define H1S    168    // H1 LDS row stride in elems (336B)

typedef __attribute__((ext_vector_type(8))) short bf16x8;
typedef __attribute__((ext_vector_type(4))) float f32x4;
typedef __attribute__((ext_vector_type(2))) float f32x2;

__device__ __forceinline__ unsigned short f2bf(float x){
    unsigned int u = __float_as_uint(x);
    return (unsigned short)((u + 0x7fffu + ((u >> 16) & 1u)) >> 16);
}
__device__ __forceinline__ float bf2f(unsigned short u){
    return __uint_as_float(((unsigned int)u) << 16);
}
__device__ __forceinline__ unsigned int cvtpk(float a, float b){
    unsigned int r; asm("v_cvt_pk_bf16_f32 %0, %1, %2" : "=v"(r) : "v"(a), "v"(b)); return r;
}
// fp8x8 (two dwords) elementwise product -> bf16x8
__device__ __forceinline__ bf16x8 f8mul8(uint2 m, uint2 a){
    f32x2 m0 = __builtin_amdgcn_cvt_pk_f32_fp8(m.x, false);
    f32x2 m1 = __builtin_amdgcn_cvt_pk_f32_fp8(m.x, true);
    f32x2 m2 = __builtin_amdgcn_cvt_pk_f32_fp8(m.y, false);
    f32x2 m3 = __builtin_amdgcn_cvt_pk_f32_fp8(m.y, true);
    f32x2 a0 = __builtin_amdgcn_cvt_pk_f32_fp8(a.x, false);
    f32x2 a1 = __builtin_amdgcn_cvt_pk_f32_fp8(a.x, true);
    f32x2 a2 = __builtin_amdgcn_cvt_pk_f32_fp8(a.y, false);
    f32x2 a3 = __builtin_amdgcn_cvt_pk_f32_fp8(a.y, true);
    uint4 r;
    r.x = cvtpk(m0[0]*a0[0], m0[1]*a0[1]);
    r.y = cvtpk(m1[0]*a1[0], m1[1]*a1[1]);
    r.z = cvtpk(m2[0]*a2[0], m2[1]*a2[1]);
    r.w = cvtpk(m3[0]*a3[0], m3[1]*a3[1]);
    return __builtin_bit_cast(bf16x8, r);
}
// 8 f32 -> bf16x8
__device__ __forceinline__ bf16x8 packf32(const float* p){
    float4 x0 = *reinterpret_cast<const float4*>(p);
    float4 x1 = *reinterpret_cast<const float4*>(p + 4);
    uint4 r;
    r.x = cvtpk(x0.x, x0.y); r.y = cvtpk(x0.z, x0.w);
    r.z = cvtpk(x1.x, x1.y); r.w = cvtpk(x1.z, x1.w);
    return __builtin_bit_cast(bf16x8, r);
}
// async global->LDS, 16B per lane, linear dest
__device__ __forceinline__ void glds16(const unsigned short* g, void* l){
    __builtin_amdgcn_global_load_lds(
        (const __attribute__((address_space(1))) unsigned int*)g,
        (__attribute__((address_space(3))) unsigned int*)l, 16, 0, 0);
}

// ---------------------------------------------------------------- prep: g_i cast to fp8 table
__global__ void k_cast_g8(const float* __restrict__ g, unsigned char* __restrict__ out, int n4){
    int c = blockIdx.x * blockDim.x + threadIdx.x;
    if (c >= n4) return;
    float4 x = reinterpret_cast<const float4*>(g)[c];
    unsigned int dw = 0;
    dw = __builtin_amdgcn_cvt_pk_fp8_f32(x.x, x.y, dw, false);
    dw = __builtin_amdgcn_cvt_pk_fp8_f32(x.z, x.w, dw, true);
    reinterpret_cast<unsigned int*>(out)[c] = dw;
}

// ---------------------------------------------------------------- prep: W1 slice -> tile-major swizzled LDS images (bf16)
__global__ void k_tiles(const float* __restrict__ W1, unsigned short* __restrict__ out, int koff){
    int idx = blockIdx.x * blockDim.x + threadIdx.x;   // granule id
    if (idx >= 8*160*8) return;
    int g  = idx & 7;
    int n  = (idx >> 3) % 160;
    int kt = idx / 1280;
    int gsrc = g ^ (n & 7);
    int k0 = koff + kt*64 + gsrc*8;
    bf16x8 v;
    #pragma unroll
    for (int e = 0; e < 8; e++){
        float x = (n < HID) ? W1[(size_t)(k0 + e) * HID + n] : 0.f;
        v[e] = (short)f2bf(x);
    }
    reinterpret_cast<bf16x8*>(out)[idx] = v;
}

// ---------------------------------------------------------------- prep: W2^T cast to bf16 [160][160]
__global__ void k_castT(const float* __restrict__ W, unsigned short* __restrict__ out,
                        int Ntot, int K, int nvalid, int kvalid, int ld, int koff){
    int idx = blockIdx.x * blockDim.x + threadIdx.x;
    int total = Ntot * K;
    if (idx >= total) return;
    int n = idx / K, k = idx - n * K;
    float v = (n < nvalid && k < kvalid) ? W[(size_t)(k + koff) * ld + n] : 0.f;
    out[idx] = f2bf(v);
}

// ---------------------------------------------------------------- prep: phi table (210 combos) @ W1_phi + b1, bf16
__global__ void k_phiw(const float* __restrict__ de, const float* __restrict__ ge,
                       const float* __restrict__ se, const float* __restrict__ W1,
                       const float* __restrict__ b1, unsigned short* __restrict__ PhiW){
    int c = blockIdx.x;      // 0..209
    int h = threadIdx.x;
    if (h >= HIDP) return;
    int si = c % 3, gi2 = (c / 3) % 7, di = c / 21;
    float acc = 0.f;
    if (h < HID){
        acc = b1[h];
        #pragma unroll
        for (int d = 0; d < 20; d++) acc += de[di*20 + d] * W1[(size_t)(1536 + d) * HID + h];
        #pragma unroll
        for (int d = 0; d < 20; d++) acc += ge[gi2*20 + d] * W1[(size_t)(1556 + d) * HID + h];
        #pragma unroll
        for (int d = 0; d < 20; d++) acc += se[si*20 + d] * W1[(size_t)(1576 + d) * HID + h];
    }
    PhiW[c * HIDP + h] = f2bf(acc);
}

// ---------------------------------------------------------------- prep: padded W3 / b2 (f32, 160)
__global__ void k_pad(const float* __restrict__ W3, const float* __restrict__ b2,
                      float* __restrict__ w3p, float* __restrict__ b2p){
    int h = threadIdx.x; if (h >= HIDP) return;
    w3p[h] = (h < HID) ? W3[h] : 0.f;
    b2p[h] = (h < HID) ? b2[h] : 0.f;
}

// ---------------------------------------------------------------- sort: zero bins + tail records
__global__ void k_zero(int* __restrict__ hist, int4* __restrict__ recs, int P, int nb){
    int i = blockIdx.x * blockDim.x + threadIdx.x;
    if (i < nb) hist[i] = 0;
    if (i < BM) recs[P + i] = (int4){0, 0, (int)0x80000000, 0};
}
// histogram of mention ids
__global__ void k_hist(const int* __restrict__ mid, int* __restrict__ hist, int P){
    int p = blockIdx.x * blockDim.x + threadIdx.x;
    if (p < P) atomicAdd(&hist[mid[p]], 1);
}
// exclusive prefix sum over nb bins (single block)
__global__ void k_scan(const int* __restrict__ hist, int* __restrict__ offsw, int nb){
    __shared__ int part[256];
    int t = threadIdx.x;
    int chunk = (nb + 255) / 256;
    int lo = t * chunk, hi = lo + chunk; if (hi > nb) hi = nb;
    int s = 0;
    for (int b = lo; b < hi; b++) s += hist[b];
    part[t] = s;
    __syncthreads();
    for (int d = 1; d < 256; d <<= 1){
        int v = (t >= d) ? part[t - d] : 0;
        __syncthreads();
        part[t] += v;
        __syncthreads();
    }
    int run = part[t] - s;
    for (int b = lo; b < hi; b++){ offsw[b] = run; run += hist[b]; }
}
// scatter packed records in mention-sorted order
__global__ void k_scatter(const int* __restrict__ mident, const int* __restrict__ antid,
                          const int* __restrict__ di, const int* __restrict__ gi, const int* __restrict__ si,
                          const int* __restrict__ seg, const int* __restrict__ pos, const float* __restrict__ ms,
                          int* __restrict__ offsw, int4* __restrict__ recs, int P){
    int p = blockIdx.x * blockDim.x + threadIdx.x;
    if (p >= P) return;
    int m = mident[p], a = antid[p];
    int idx = atomicAdd(&offsw[m], 1);
    int combo = (di[p] * 7 + gi[p]) * 3 + si[p];
    int meta = (combo << 19) | (seg[p] << 5) | pos[p];
    int4 r; r.x = m; r.y = a; r.z = meta; r.w = __float_as_int(ms[m] + ms[a]);
    recs[idx] = r;
}

// ================================================================ phase 1: Am/Aa projections (f32 in, fp8 out)
__global__ __launch_bounds__(256, 3) void k_proj(const float* __restrict__ g_i,
                                                 const unsigned short* __restrict__ Wtiles,
                                                 unsigned char* __restrict__ out){
    __shared__ char smem[40960];                      // 2 x 20480 B buffers
    const unsigned short* Wt = Wtiles + (size_t)blockIdx.y * 81920;
    unsigned char* outh = out + (size_t)blockIdx.y * NROWS * HIDP;
    int tid = threadIdx.x, lane = tid & 63, w = tid >> 6;
    int l15 = lane & 15, lh = lane >> 4;
    int swz = (l15 & 7) << 4;
    int row0 = blockIdx.x * BM;

    int r0 = row0 + 32*w + l15;       int r0c = (r0 < NROWS) ? r0 : NROWS - 1;
    int r1 = r0 + 16;                 int r1c = (r1 < NROWS) ? r1 : NROWS - 1;
    const float* gp0 = g_i + (size_t)r0c * GDIM + lh * 8;
    const float* gp1 = g_i + (size_t)r1c * GDIM + lh * 8;

    f32x4 acc1[10][2];
    #pragma unroll
    for (int t = 0; t < 10; t++){ acc1[t][0] = (f32x4){0,0,0,0}; acc1[t][1] = (f32x4){0,0,0,0}; }

#define STAGEP(kt, dst) do{ \
    _Pragma("unroll") \
    for (int i_ = 0; i_ < 5; i_++){ \
        int c_ = w*5 + i_; \
        glds16(Wt + (size_t)(kt)*10240 + c_*512 + lane*8, (dst) + c_*1024); \
    } \
}while(0)
#define LOADAP(kt, R) do{ \
    R[0] = packf32(gp0 + (kt)*64);      R[1] = packf32(gp0 + (kt)*64 + 32); \
    R[2] = packf32(gp1 + (kt)*64);      R[3] = packf32(gp1 + (kt)*64 + 32); \
}while(0)
#define PHASEP(A, buf) do{ \
    _Pragma("unroll") \
    for (int kh = 0; kh < 2; kh++){ \
        int off_ = l15*128 + ((kh*64 + lh*16) ^ swz); \
        _Pragma("unroll") \
        for (int t = 0; t < 10; t++){ \
            bf16x8 wf = *reinterpret_cast<const bf16x8*>((buf) + t*2048 + off_); \
            acc1[t][0] = __builtin_amdgcn_mfma_f32_16x16x32_bf16(wf, A[kh],   acc1[t][0], 0,0,0); \
            acc1[t][1] = __builtin_amdgcn_mfma_f32_16x16x32_bf16(wf, A[2+kh], acc1[t][1], 0,0,0); \
        } \
    } \
}while(0)

    bf16x8 A0[4], A1[4];
    STAGEP(0, smem);
    LOADAP(0, A0);
    __syncthreads();
    #pragma unroll
    for (int kt2 = 0; kt2 < 8; kt2 += 2){
        STAGEP(kt2+1, smem + 20480); LOADAP(kt2+1, A1);
        PHASEP(A0, smem);
        __syncthreads();
        if (kt2 + 2 < 8){ STAGEP(kt2+2, smem); LOADAP(kt2+2, A0); }
        PHASEP(A1, smem + 20480);
        __syncthreads();
    }

    // epilogue: 4 consecutive h per lane -> fp8 dword stores
    #pragma unroll
    for (int rf = 0; rf < 2; rf++){
        int row = row0 + 32*w + 16*rf + l15;
        if (row < NROWS){
            #pragma unroll
            for (int t = 0; t < 10; t++){
                f32x4 a = acc1[t][rf];
                unsigned int dw = 0;
                dw = __builtin_amdgcn_cvt_pk_fp8_f32(a[0], a[1], dw, false);
                dw = __builtin_amdgcn_cvt_pk_fp8_f32(a[2], a[3], dw, true);
                *reinterpret_cast<unsigned int*>(outh + (size_t)row * HIDP + 16*t + 4*lh) = dw;
            }
        }
    }
#undef STAGEP
#undef LOADAP
#undef PHASEP
}

// ================================================================ fused pair scorer (sorted records, fp8 gathers)
__global__ __launch_bounds__(256, 3) void k_fused(
    const unsigned char* __restrict__ g8,
    const unsigned short* __restrict__ Wc_tiles, const unsigned short* __restrict__ W2T,
    const unsigned short* __restrict__ PhiW, const unsigned char* __restrict__ Am,
    const unsigned char* __restrict__ Aa,
    const float* __restrict__ w3p, const float* __restrict__ b2p, const float* __restrict__ b3,
    const int4* __restrict__ recs,
    float* __restrict__ dense)
{
    __shared__ char smem[43008];          // [0,20480) buf0 | [20480,40960) buf1 ; alias H1[128][168] bf16
    int tid = threadIdx.x, lane = tid & 63, w = tid >> 6;
    int l15 = lane & 15, lh = lane >> 4;
    int swz = (l15 & 7) << 4;
    int p0 = blockIdx.x * BM;

    int4 rec0 = recs[p0 + 32*w + l15];
    int4 rec1 = recs[p0 + 32*w + 16 + l15];

    const unsigned char* gm0 = g8 + (size_t)rec0.x * GDIM;
    const unsigned char* ga0 = g8 + (size_t)rec0.y * GDIM;
    const unsigned char* gm1 = g8 + (size_t)rec1.x * GDIM;
    const unsigned char* ga1 = g8 + (size_t)rec1.y * GDIM;

    f32x4 acc1[10][2];
    #pragma unroll
    for (int t = 0; t < 10; t++){ acc1[t][0] = (f32x4){0,0,0,0}; acc1[t][1] = (f32x4){0,0,0,0}; }

#define STAGEF(kt, dst) do{ \
    _Pragma("unroll") \
    for (int i_ = 0; i_ < 5; i_++){ \
        int c_ = w*5 + i_; \
        glds16(Wc_tiles + (size_t)(kt)*10240 + c_*512 + lane*8, (dst) + c_*1024); \
    } \
}while(0)
#define LOADAF(kt, R) do{ \
    R[0] = *reinterpret_cast<const uint2*>(gm0 + (kt)*64 + lh*8); \
    R[1] = *reinterpret_cast<const uint2*>(ga0 + (kt)*64 + lh*8); \
    R[2] = *reinterpret_cast<const uint2*>(gm0 + (kt)*64 + 32 + lh*8); \
    R[3] = *reinterpret_cast<const uint2*>(ga0 + (kt)*64 + 32 + lh*8); \
    R[4] = *reinterpret_cast<const uint2*>(gm1 + (kt)*64 + lh*8); \
    R[5] = *reinterpret_cast<const uint2*>(ga1 + (kt)*64 + lh*8); \
    R[6] = *reinterpret_cast<const uint2*>(gm1 + (kt)*64 + 32 + lh*8); \
    R[7] = *reinterpret_cast<const uint2*>(ga1 + (kt)*64 + 32 + lh*8); \
}while(0)
#define PHASEF(A, buf) do{ \
    _Pragma("unroll") \
    for (int kh = 0; kh < 2; kh++){ \
        bf16x8 pv0 = f8mul8(A[0 + kh*2], A[1 + kh*2]); \
        bf16x8 pv1 = f8mul8(A[4 + kh*2], A[5 + kh*2]); \
        int off_ = l15*128 + ((kh*64 + lh*16) ^ swz); \
        _Pragma("unroll") \
        for (int t = 0; t < 10; t++){ \
            bf16x8 wf = *reinterpret_cast<const bf16x8*>((buf) + t*2048 + off_); \
            acc1[t][0] = __builtin_amdgcn_mfma_f32_16x16x32_bf16(wf, pv0, acc1[t][0], 0,0,0); \
            acc1[t][1] = __builtin_amdgcn_mfma_f32_16x16x32_bf16(wf, pv1, acc1[t][1], 0,0,0); \
        } \
    } \
}while(0)

    uint2 A0[8], A1[8];
    STAGEF(0, smem);
    LOADAF(0, A0);
    __syncthreads();
    #pragma unroll
    for (int kt2 = 0; kt2 < 8; kt2 += 2){
        STAGEF(kt2+1, smem + 20480); LOADAF(kt2+1, A1);
        PHASEF(A0, smem);
        __syncthreads();
        if (kt2 + 2 < 8){ STAGEF(kt2+2, smem); LOADAF(kt2+2, A0); }
        PHASEF(A1, smem + 20480);
        __syncthreads();
    }
    // smem becomes H1 [128][H1S] bf16 (per-wave private slabs)

    // ---- epilogue 1: + Am + Aa + PhiW, relu, bf16-pack -> H1
    #pragma unroll
    for (int rf = 0; rf < 2; rf++){
        int4 rc = rf ? rec1 : rec0;
        int pr = 32*w + 16*rf + l15;
        const unsigned char* amp = Am + (size_t)rc.x * HIDP;
        const unsigned char* aap = Aa + (size_t)rc.y * HIDP;
        int combo = (rc.z >> 19) & 0xFF;
        const unsigned short* php = PhiW + (size_t)combo * HIDP;
        char* h1row = smem + pr * (H1S*2);
        #pragma unroll
        for (int t = 0; t < 10; t++){
            int h0 = 16*t + 4*lh;
            unsigned int amd = *reinterpret_cast<const unsigned int*>(amp + h0);
            unsigned int aad = *reinterpret_cast<const unsigned int*>(aap + h0);
            ushort4 ph4 = *reinterpret_cast<const ushort4*>(php + h0);
            f32x2 amL = __builtin_amdgcn_cvt_pk_f32_fp8(amd, false);
            f32x2 amH = __builtin_amdgcn_cvt_pk_f32_fp8(amd, true);
            f32x2 aaL = __builtin_amdgcn_cvt_pk_f32_fp8(aad, false);
            f32x2 aaH = __builtin_amdgcn_cvt_pk_f32_fp8(aad, true);
            f32x4 a = acc1[t][rf];
            float v0 = fmaxf(a[0] + amL[0] + aaL[0] + bf2f(ph4.x), 0.f);
            float v1 = fmaxf(a[1] + amL[1] + aaL[1] + bf2f(ph4.y), 0.f);
            float v2 = fmaxf(a[2] + amH[0] + aaH[0] + bf2f(ph4.z), 0.f);
            float v3 = fmaxf(a[3] + amH[1] + aaH[1] + bf2f(ph4.w), 0.f);
            uint2 pk; pk.x = cvtpk(v0, v1); pk.y = cvtpk(v2, v3);
            *reinterpret_cast<uint2*>(h1row + h0*2) = pk;
        }
    }

    // ---- GEMM2: H2 = H1 @ W2 (H1 frags from own-wave LDS slab, W2 frags from global)
    f32x4 acc2[10][2];
    #pragma unroll
    for (int t = 0; t < 10; t++){ acc2[t][0] = (f32x4){0,0,0,0}; acc2[t][1] = (f32x4){0,0,0,0}; }
    const unsigned short* w2pb = W2T + (size_t)l15 * HIDP + lh * 8;
    #pragma unroll
    for (int k2 = 0; k2 < 5; k2++){
        bf16x8 h0f = *reinterpret_cast<const bf16x8*>(smem + (32*w + l15)      * (H1S*2) + k2*64 + lh*16);
        bf16x8 h1f = *reinterpret_cast<const bf16x8*>(smem + (32*w + 16 + l15) * (H1S*2) + k2*64 + lh*16);
        #pragma unroll
        for (int t = 0; t < 10; t++){
            bf16x8 wf = *reinterpret_cast<const bf16x8*>(w2pb + t * 16 * HIDP + k2 * 32);
            acc2[t][0] = __builtin_amdgcn_mfma_f32_16x16x32_bf16(wf, h0f, acc2[t][0], 0,0,0);
            acc2[t][1] = __builtin_amdgcn_mfma_f32_16x16x32_bf16(wf, h1f, acc2[t][1], 0,0,0);
        }
    }

    // ---- epilogue 2: relu(+b2), dot W3, + ms sum, scatter
    float b3v = b3[0];
    #pragma unroll
    for (int rf = 0; rf < 2; rf++){
        int4 rc = rf ? rec1 : rec0;
        float s = 0.f;
        #pragma unroll
        for (int t = 0; t < 10; t++){
            f32x4 w3v = *reinterpret_cast<const f32x4*>(w3p + 16*t + 4*lh);
            f32x4 b2v = *reinterpret_cast<const f32x4*>(b2p + 16*t + 4*lh);
            f32x4 a = acc2[t][rf];
            s += fmaxf(a[0] + b2v[0], 0.f) * w3v[0];
            s += fmaxf(a[1] + b2v[1], 0.f) * w3v[1];
            s += fmaxf(a[2] + b2v[2], 0.f) * w3v[2];
            s += fmaxf(a[3] + b2v[3], 0.f) * w3v[3];
        }
        s += __shfl_xor(s, 16);
        s += __shfl_xor(s, 32);
        if (!(rc.z & 0x80000000) && lh == 0){
            float val = s + b3v + __int_as_float(rc.w);
            dense[(size_t)((rc.z >> 5) & 0x3FFF) * KP1 + (rc.z & 31)] = val;
        }
    }
#undef STAGEF
#undef LOADAF
#undef PHASEF
}

// ---------------------------------------------------------------- phase 4: segment softmax
__global__ void k_softmax(const float* __restrict__ dense, const int* __restrict__ seg_lengths,
                          float* __restrict__ out, int S){
    int wid = threadIdx.x >> 6, lane = threadIdx.x & 63;
    int s = blockIdx.x * 4 + wid;
    if (s >= S) return;
    int len = seg_lengths[s];
    float ninf = -__builtin_inff();
    float val = ninf;
    if (lane < KP1) val = (lane < len) ? dense[(size_t)s * KP1 + lane] : ((lane == len) ? 0.f : ninf);
    float m = val;
    #pragma unroll
    for (int msk = 1; msk < 64; msk <<= 1) m = fmaxf(m, __shfl_xor(m, msk));
    float e = expf(val - m);
    float sum = e;
    #pragma unroll
    for (int msk = 1; msk < 64; msk <<= 1) sum += __shfl_xor(sum, msk);
    if (lane < KP1) out[(size_t)s * KP1 + lane] = (lane > len) ? 1000.f : (e / sum);
}

// ---------------------------------------------------------------- launch
extern "C" void kernel_launch(void* const* d_in, const int* in_sizes, int n_in,
                              void* d_out, int out_size, void* d_ws, size_t ws_size,
                              hipStream_t stream){
    const float* g_i        = (const float*)d_in[0];
    const float* ms         = (const float*)d_in[1];
    const float* dist_emb   = (const float*)d_in[2];
    const float* genre_emb  = (const float*)d_in[3];
    const float* spk_emb    = (const float*)d_in[4];
    const float* W1         = (const float*)d_in[5];
    const float* b1         = (const float*)d_in[6];
    const float* W2         = (const float*)d_in[7];
    const float* b2         = (const float*)d_in[8];
    const float* W3         = (const float*)d_in[9];
    const float* b3         = (const float*)d_in[10];
    const int* mention_ids  = (const int*)d_in[11];
    const int* antecedent_ids = (const int*)d_in[12];
    const int* dist_idx     = (const int*)d_in[13];
    const int* genre_idx    = (const int*)d_in[14];
    const int* spk_idx      = (const int*)d_in[15];
    const int* seg_ids      = (const int*)d_in[16];
    const int* pos_in_seg   = (const int*)d_in[17];
    const int* seg_lengths  = (const int*)d_in[18];
    int P = in_sizes[11];
    int S = in_sizes[18];

    char* ws = (char*)d_ws;
    unsigned short* W1ab_tiles = (unsigned short*)(ws + 0);        // 2 x 163840
    unsigned short* W1c_tiles  = (unsigned short*)(ws + 327680);   // 163840 -> 491520
    unsigned short* W2T        = (unsigned short*)(ws + 491520);   // 51200  -> 542720
    unsigned short* PhiW       = (unsigned short*)(ws + 542720);   // 67200  -> 609920
    float* w3pad               = (float*)(ws + 609920);            // 640    -> 610560
    float* b2pad               = (float*)(ws + 610560);            // 640    -> 611200
    unsigned char* g8          = (unsigned char*)(ws + 611200);    // 6144000  -> 6755200
    unsigned char* Am8         = (unsigned char*)(ws + 6755200);   // 1920000  -> 8675200
    unsigned char* Aa8         = (unsigned char*)(ws + 8675200);   // 1920000  -> 10595200
    int* hist                  = (int*)(ws + 10595200);            // 48128    -> 10643328
    int* offsw                 = (int*)(ws + 10643328);            // 48128    -> 10691456
    int4* recs                 = (int4*)(ws + 10691456);           // (P+128)*16 ~ 2.5MB -> ~13.2MB
    float* dense               = (float*)(ws + 13402112);          // 10001*31*4

    // prep + sort
    k_zero<<<47, 256, 0, stream>>>(hist, recs, P, NROWS);
    k_cast_g8<<<(NROWS*GDIM/4 + 255)/256, 256, 0, stream>>>(g_i, g8, NROWS*GDIM/4);
    k_tiles<<<40, 256, 0, stream>>>(W1, W1ab_tiles,          0);
    k_tiles<<<40, 256, 0, stream>>>(W1, W1ab_tiles + 81920,  512);
    k_tiles<<<40, 256, 0, stream>>>(W1, W1c_tiles,           1024);
    k_castT<<<(160*160 + 255)/256, 256, 0, stream>>>(W2, W2T, 160, 160, HID, HID, HID, 0);
    k_phiw<<<210, 192, 0, stream>>>(dist_emb, genre_emb, spk_emb, W1, b1, PhiW);
    k_pad<<<1, 192, 0, stream>>>(W3, b2, w3pad, b2pad);
    k_hist<<<(P + 255)/256, 256, 0, stream>>>(mention_ids, hist, P);
    k_scan<<<1, 256, 0, stream>>>(hist, offsw, NROWS);
    k_scatter<<<(P + 255)/256, 256, 0, stream>>>(mention_ids, antecedent_ids, dist_idx, genre_idx,
        spk_idx, seg_ids, pos_in_seg, ms, offsw, recs, P);

    // row projections Am / Aa (fp8 out)
    k_proj<<<dim3((NROWS + BM - 1)/BM, 2), 256, 0, stream>>>(g_i, W1ab_tiles, Am8);
    // note: second y-slice writes Aa8 = Am8 + NROWS*HIDP (contiguous)

    // fused pair scorer
    k_fused<<<(P + BM - 1)/BM, 256, 0, stream>>>(g8, W1c_tiles, W2T, PhiW,
        Am8, Aa8, w3pad, b2pad, b3, recs, dense);

    // segment softmax
    k_softmax<<<(S + 3)/4, 256, 0, stream>>>(dense, seg_lengths, (float*)d_out, S);
}

// Round 6
// 144.245 us; speedup vs baseline: 1.1834x; 1.1834x over previous
//
#include <hip/hip_runtime.h>
#include <stdint.h>

#define GDIM   512
#define HID    150
#define HIDP   160    // HID padded to multiple of 16
#define NROWS  12000
#define KP1    31     // KMAX+1
#define BM     128    // pairs (or rows) per block
#define H1S    168    // H1 LDS row stride in elems (336B)

typedef __attribute__((ext_vector_type(8))) short bf16x8;
typedef __attribute__((ext_vector_type(4))) float f32x4;
typedef __attribute__((ext_vector_type(2))) float f32x2;

__device__ __forceinline__ unsigned short f2bf(float x){
    unsigned int u = __float_as_uint(x);
    return (unsigned short)((u + 0x7fffu + ((u >> 16) & 1u)) >> 16);
}
__device__ __forceinline__ float bf2f(unsigned short u){
    return __uint_as_float(((unsigned int)u) << 16);
}
__device__ __forceinline__ unsigned int cvtpk(float a, float b){
    unsigned int r; asm("v_cvt_pk_bf16_f32 %0, %1, %2" : "=v"(r) : "v"(a), "v"(b)); return r;
}
// fp8x8 (two dwords) elementwise product -> bf16x8
__device__ __forceinline__ bf16x8 f8mul8(uint2 m, uint2 a){
    f32x2 m0 = __builtin_amdgcn_cvt_pk_f32_fp8(m.x, false);
    f32x2 m1 = __builtin_amdgcn_cvt_pk_f32_fp8(m.x, true);
    f32x2 m2 = __builtin_amdgcn_cvt_pk_f32_fp8(m.y, false);
    f32x2 m3 = __builtin_amdgcn_cvt_pk_f32_fp8(m.y, true);
    f32x2 a0 = __builtin_amdgcn_cvt_pk_f32_fp8(a.x, false);
    f32x2 a1 = __builtin_amdgcn_cvt_pk_f32_fp8(a.x, true);
    f32x2 a2 = __builtin_amdgcn_cvt_pk_f32_fp8(a.y, false);
    f32x2 a3 = __builtin_amdgcn_cvt_pk_f32_fp8(a.y, true);
    uint4 r;
    r.x = cvtpk(m0[0]*a0[0], m0[1]*a0[1]);
    r.y = cvtpk(m1[0]*a1[0], m1[1]*a1[1]);
    r.z = cvtpk(m2[0]*a2[0], m2[1]*a2[1]);
    r.w = cvtpk(m3[0]*a3[0], m3[1]*a3[1]);
    return __builtin_bit_cast(bf16x8, r);
}
// fp8x8 -> bf16x8 (no mul)
__device__ __forceinline__ bf16x8 f8cvt8(uint2 m){
    f32x2 m0 = __builtin_amdgcn_cvt_pk_f32_fp8(m.x, false);
    f32x2 m1 = __builtin_amdgcn_cvt_pk_f32_fp8(m.x, true);
    f32x2 m2 = __builtin_amdgcn_cvt_pk_f32_fp8(m.y, false);
    f32x2 m3 = __builtin_amdgcn_cvt_pk_f32_fp8(m.y, true);
    uint4 r;
    r.x = cvtpk(m0[0], m0[1]);
    r.y = cvtpk(m1[0], m1[1]);
    r.z = cvtpk(m2[0], m2[1]);
    r.w = cvtpk(m3[0], m3[1]);
    return __builtin_bit_cast(bf16x8, r);
}
// async global->LDS, 16B per lane, linear dest
__device__ __forceinline__ void glds16(const unsigned short* g, void* l){
    __builtin_amdgcn_global_load_lds(
        (const __attribute__((address_space(1))) unsigned int*)g,
        (__attribute__((address_space(3))) unsigned int*)l, 16, 0, 0);
}

#define SB0 __builtin_amdgcn_sched_barrier(0)
// counted barrier: leave n A-loads in flight, drain glds (FIFO vmcnt) + own ds_reads
#define BARN(n) do{ asm volatile("s_waitcnt vmcnt(" #n ") lgkmcnt(0)" ::: "memory"); \
                    __builtin_amdgcn_s_barrier(); }while(0)
#define BARE    do{ asm volatile("s_waitcnt lgkmcnt(0)" ::: "memory"); \
                    __builtin_amdgcn_s_barrier(); }while(0)

// ---------------------------------------------------------------- prep0: zero hist, sentinel recs, g8 cast (permuted), W1 tiles
// g8 row layout per 64-col tile: [lh][kh][8] : out[row*512 + kt*64 + lh*16 + kh*8 + e] = fp8(g[row, kt*64 + kh*32 + lh*8 + e])
__global__ void k_prep0(const float* __restrict__ g, unsigned char* __restrict__ g8,
                        int* __restrict__ hist, int4* __restrict__ recs,
                        const float* __restrict__ W1, unsigned short* __restrict__ Wtiles, int P){
    int i = blockIdx.x * blockDim.x + threadIdx.x;
    if (i < NROWS) hist[i] = 0;
    if (i < BM) recs[P + i] = (int4){0, 0, (int)0x80000000, 0};
    if (i < 30720){
        // W1 tiles: 3 slices (a, b, c), swizzled tile-major images
        int s = i / 10240, r = i % 10240;
        int gg = r & 7, n = (r >> 3) % 160, kt = r / 1280;
        int gsrc = gg ^ (n & 7);
        int k0 = s * 512 + kt * 64 + gsrc * 8;
        bf16x8 v;
        #pragma unroll
        for (int e = 0; e < 8; e++){
            float x = (n < HID) ? W1[(size_t)(k0 + e) * HID + n] : 0.f;
            v[e] = (short)f2bf(x);
        }
        reinterpret_cast<bf16x8*>(Wtiles)[i] = v;
    }
    if (i >= NROWS * 32) return;
    int lh = i & 3, kt = (i >> 2) & 7, row = i >> 5;
    const float* src = g + (size_t)row * 512 + kt * 64 + lh * 8;
    float4 x0 = *reinterpret_cast<const float4*>(src);
    float4 x1 = *reinterpret_cast<const float4*>(src + 4);
    float4 x2 = *reinterpret_cast<const float4*>(src + 32);
    float4 x3 = *reinterpret_cast<const float4*>(src + 36);
    uint4 o; unsigned int d;
    d = 0; d = __builtin_amdgcn_cvt_pk_fp8_f32(x0.x, x0.y, d, false);
    d = __builtin_amdgcn_cvt_pk_fp8_f32(x0.z, x0.w, d, true);  o.x = d;
    d = 0; d = __builtin_amdgcn_cvt_pk_fp8_f32(x1.x, x1.y, d, false);
    d = __builtin_amdgcn_cvt_pk_fp8_f32(x1.z, x1.w, d, true);  o.y = d;
    d = 0; d = __builtin_amdgcn_cvt_pk_fp8_f32(x2.x, x2.y, d, false);
    d = __builtin_amdgcn_cvt_pk_fp8_f32(x2.z, x2.w, d, true);  o.z = d;
    d = 0; d = __builtin_amdgcn_cvt_pk_fp8_f32(x3.x, x3.y, d, false);
    d = __builtin_amdgcn_cvt_pk_fp8_f32(x3.z, x3.w, d, true);  o.w = d;
    *reinterpret_cast<uint4*>(g8 + (size_t)row * 512 + kt * 64 + lh * 16) = o;
}

// ---------------------------------------------------------------- wprep: PhiW table + W3/b2 pad + W2^T cast
__global__ void k_wprep(const float* __restrict__ de, const float* __restrict__ ge,
                        const float* __restrict__ se, const float* __restrict__ W1,
                        const float* __restrict__ b1, const float* __restrict__ W2,
                        const float* __restrict__ W3, const float* __restrict__ b2,
                        unsigned short* __restrict__ PhiW, unsigned short* __restrict__ W2T,
                        float* __restrict__ w3p, float* __restrict__ b2p){
    int c = blockIdx.x, tid = threadIdx.x;
    if (c < 210 && tid < HIDP){
        int si = c % 3, gi2 = (c / 3) % 7, di = c / 21;
        float acc = 0.f;
        if (tid < HID){
            acc = b1[tid];
            #pragma unroll
            for (int dd = 0; dd < 20; dd++) acc += de[di*20 + dd] * W1[(size_t)(1536 + dd) * HID + tid];
            #pragma unroll
            for (int dd = 0; dd < 20; dd++) acc += ge[gi2*20 + dd] * W1[(size_t)(1556 + dd) * HID + tid];
            #pragma unroll
            for (int dd = 0; dd < 20; dd++) acc += se[si*20 + dd] * W1[(size_t)(1576 + dd) * HID + tid];
        }
        PhiW[c * HIDP + tid] = f2bf(acc);
    }
    if (c == 210 && tid < HIDP){
        w3p[tid] = (tid < HID) ? W3[tid] : 0.f;
        b2p[tid] = (tid < HID) ? b2[tid] : 0.f;
    }
    int idx = c * 128 + (tid & 127);
    if (tid < 128 && idx < 160 * 160){
        int n = idx / 160, k = idx - n * 160;
        float v = (n < HID && k < HID) ? W2[(size_t)k * HID + n] : 0.f;
        W2T[idx] = f2bf(v);
    }
}

// ---------------------------------------------------------------- sort kernels
__global__ void k_hist(const int* __restrict__ mid, int* __restrict__ hist, int P){
    int p = blockIdx.x * blockDim.x + threadIdx.x;
    if (p < P) atomicAdd(&hist[mid[p]], 1);
}
__global__ void k_scan(const int* __restrict__ hist, int* __restrict__ offsw, int nb){
    __shared__ int part[1024];
    int t = threadIdx.x;
    int chunk = (nb + 1023) / 1024;
    int lo = t * chunk, hi = lo + chunk; if (hi > nb) hi = nb;
    int s = 0;
    for (int b = lo; b < hi; b++) s += hist[b];
    part[t] = s;
    __syncthreads();
    for (int d = 1; d < 1024; d <<= 1){
        int v = (t >= d) ? part[t - d] : 0;
        __syncthreads();
        part[t] += v;
        __syncthreads();
    }
    int run = part[t] - s;
    for (int b = lo; b < hi; b++){ offsw[b] = run; run += hist[b]; }
}
__global__ void k_scatter(const int* __restrict__ mident, const int* __restrict__ antid,
                          const int* __restrict__ di, const int* __restrict__ gi, const int* __restrict__ si,
                          const int* __restrict__ seg, const int* __restrict__ pos, const float* __restrict__ ms,
                          int* __restrict__ offsw, int4* __restrict__ recs, int P){
    int p = blockIdx.x * blockDim.x + threadIdx.x;
    if (p >= P) return;
    int m = mident[p], a = antid[p];
    int idx = atomicAdd(&offsw[m], 1);
    int combo = (di[p] * 7 + gi[p]) * 3 + si[p];
    int meta = (combo << 19) | (seg[p] << 5) | pos[p];
    int4 r; r.x = m; r.y = a; r.z = meta; r.w = __float_as_int(ms[m] + ms[a]);
    recs[idx] = r;
}

// ================================================================ phase 1: Am/Aa projections (fp8 in, fp8 out)
__global__ __launch_bounds__(256, 3) void k_proj(const unsigned char* __restrict__ g8,
                                                 const unsigned short* __restrict__ Wtiles,
                                                 unsigned char* __restrict__ out){
    __shared__ char smem[40960];                      // 2 x 20480 B buffers
    const unsigned short* Wt = Wtiles + (size_t)blockIdx.y * 81920;
    unsigned char* outh = out + (size_t)blockIdx.y * NROWS * HIDP;
    int tid = threadIdx.x, lane = tid & 63, w = tid >> 6;
    int l15 = lane & 15, lh = lane >> 4;
    int swz = (l15 & 7) << 4;
    int row0 = blockIdx.x * BM;

    int r0 = row0 + 32*w + l15;       int r0c = (r0 < NROWS) ? r0 : NROWS - 1;
    int r1 = r0 + 16;                 int r1c = (r1 < NROWS) ? r1 : NROWS - 1;
    const unsigned char* gp0 = g8 + (size_t)r0c * GDIM + lh * 16;
    const unsigned char* gp1 = g8 + (size_t)r1c * GDIM + lh * 16;

    f32x4 acc1[10][2];
    #pragma unroll
    for (int t = 0; t < 10; t++){ acc1[t][0] = (f32x4){0,0,0,0}; acc1[t][1] = (f32x4){0,0,0,0}; }

#define STAGEP(kt, dst) do{ \
    _Pragma("unroll") \
    for (int i_ = 0; i_ < 5; i_++){ \
        int c_ = w*5 + i_; \
        glds16(Wt + (size_t)(kt)*10240 + c_*512 + lane*8, (dst) + c_*1024); \
    } \
}while(0)
#define LOADAP(kt, R) do{ \
    R[0] = *reinterpret_cast<const uint4*>(gp0 + (kt)*64); \
    R[1] = *reinterpret_cast<const uint4*>(gp1 + (kt)*64); \
}while(0)
#define PHASEP(A, buf) do{ \
    _Pragma("unroll") \
    for (int kh = 0; kh < 2; kh++){ \
        uint2 q0_, q1_; \
        q0_.x = (kh==0)?A[0].x:A[0].z;  q0_.y = (kh==0)?A[0].y:A[0].w; \
        q1_.x = (kh==0)?A[1].x:A[1].z;  q1_.y = (kh==0)?A[1].y:A[1].w; \
        bf16x8 a0_ = f8cvt8(q0_), a1_ = f8cvt8(q1_); \
        int off_ = l15*128 + ((kh*64 + lh*16) ^ swz); \
        _Pragma("unroll") \
        for (int t = 0; t < 10; t++){ \
            bf16x8 wf = *reinterpret_cast<const bf16x8*>((buf) + t*2048 + off_); \
            acc1[t][0] = __builtin_amdgcn_mfma_f32_16x16x32_bf16(wf, a0_, acc1[t][0], 0,0,0); \
            acc1[t][1] = __builtin_amdgcn_mfma_f32_16x16x32_bf16(wf, a1_, acc1[t][1], 0,0,0); \
        } \
    } \
}while(0)

    uint4 A0[2], A1[2];
    STAGEP(0, smem); SB0;
    LOADAP(0, A0); SB0;
    BARN(2);
    #pragma unroll
    for (int kt2 = 0; kt2 < 8; kt2 += 2){
        STAGEP(kt2+1, smem + 20480); SB0;
        LOADAP(kt2+1, A1); SB0;
        PHASEP(A0, smem);
        BARN(2);
        if (kt2 + 2 < 8){
            STAGEP(kt2+2, smem); SB0;
            LOADAP(kt2+2, A0); SB0;
        }
        PHASEP(A1, smem + 20480);
        if (kt2 + 2 < 8) BARN(2);
    }

    // epilogue: 4 consecutive h per lane -> fp8 dword stores
    #pragma unroll
    for (int rf = 0; rf < 2; rf++){
        int row = row0 + 32*w + 16*rf + l15;
        if (row < NROWS){
            #pragma unroll
            for (int t = 0; t < 10; t++){
                f32x4 a = acc1[t][rf];
                unsigned int dw = 0;
                dw = __builtin_amdgcn_cvt_pk_fp8_f32(a[0], a[1], dw, false);
                dw = __builtin_amdgcn_cvt_pk_fp8_f32(a[2], a[3], dw, true);
                *reinterpret_cast<unsigned int*>(outh + (size_t)row * HIDP + 16*t + 4*lh) = dw;
            }
        }
    }
#undef STAGEP
#undef LOADAP
#undef PHASEP
}

// ================================================================ fused pair scorer (sorted records, fp8 gathers, counted-vmcnt pipeline)
__global__ __launch_bounds__(256, 3) void k_fused(
    const unsigned char* __restrict__ g8,
    const unsigned short* __restrict__ Wc_tiles, const unsigned short* __restrict__ W2T,
    const unsigned short* __restrict__ PhiW, const unsigned char* __restrict__ Am,
    const unsigned char* __restrict__ Aa,
    const float* __restrict__ w3p, const float* __restrict__ b2p, const float* __restrict__ b3,
    const int4* __restrict__ recs,
    float* __restrict__ dense)
{
    __shared__ char smem[43008];          // [0,20480) buf0 | [20480,40960) buf1 ; alias H1[128][168] bf16
    int tid = threadIdx.x, lane = tid & 63, w = tid >> 6;
    int l15 = lane & 15, lh = lane >> 4;
    int swz = (l15 & 7) << 4;
    int p0 = blockIdx.x * BM;

    int4 rec0 = recs[p0 + 32*w + l15];
    int4 rec1 = recs[p0 + 32*w + 16 + l15];

    const unsigned char* gm0 = g8 + (size_t)rec0.x * GDIM + lh * 16;
    const unsigned char* ga0 = g8 + (size_t)rec0.y * GDIM + lh * 16;
    const unsigned char* gm1 = g8 + (size_t)rec1.x * GDIM + lh * 16;
    const unsigned char* ga1 = g8 + (size_t)rec1.y * GDIM + lh * 16;

    f32x4 acc1[10][2];
    #pragma unroll
    for (int t = 0; t < 10; t++){ acc1[t][0] = (f32x4){0,0,0,0}; acc1[t][1] = (f32x4){0,0,0,0}; }

#define STAGEF(kt, dst) do{ \
    _Pragma("unroll") \
    for (int i_ = 0; i_ < 5; i_++){ \
        int c_ = w*5 + i_; \
        glds16(Wc_tiles + (size_t)(kt)*10240 + c_*512 + lane*8, (dst) + c_*1024); \
    } \
}while(0)
#define LOADAF(kt, R) do{ \
    R[0] = *reinterpret_cast<const uint4*>(gm0 + (kt)*64); \
    R[1] = *reinterpret_cast<const uint4*>(ga0 + (kt)*64); \
    R[2] = *reinterpret_cast<const uint4*>(gm1 + (kt)*64); \
    R[3] = *reinterpret_cast<const uint4*>(ga1 + (kt)*64); \
}while(0)
#define PHASEF(A, buf) do{ \
    _Pragma("unroll") \
    for (int kh = 0; kh < 2; kh++){ \
        uint2 m0_, a0_, m1_, a1_; \
        m0_.x = (kh==0)?A[0].x:A[0].z;  m0_.y = (kh==0)?A[0].y:A[0].w; \
        a0_.x = (kh==0)?A[1].x:A[1].z;  a0_.y = (kh==0)?A[1].y:A[1].w; \
        m1_.x = (kh==0)?A[2].x:A[2].z;  m1_.y = (kh==0)?A[2].y:A[2].w; \
        a1_.x = (kh==0)?A[3].x:A[3].z;  a1_.y = (kh==0)?A[3].y:A[3].w; \
        bf16x8 pv0 = f8mul8(m0_, a0_); \
        bf16x8 pv1 = f8mul8(m1_, a1_); \
        int off_ = l15*128 + ((kh*64 + lh*16) ^ swz); \
        _Pragma("unroll") \
        for (int t = 0; t < 10; t++){ \
            bf16x8 wf = *reinterpret_cast<const bf16x8*>((buf) + t*2048 + off_); \
            acc1[t][0] = __builtin_amdgcn_mfma_f32_16x16x32_bf16(wf, pv0, acc1[t][0], 0,0,0); \
            acc1[t][1] = __builtin_amdgcn_mfma_f32_16x16x32_bf16(wf, pv1, acc1[t][1], 0,0,0); \
        } \
    } \
}while(0)

    uint4 A0[4], A1[4];
    STAGEF(0, smem); SB0;
    LOADAF(0, A0); SB0;
    BARN(4);
    #pragma unroll
    for (int kt2 = 0; kt2 < 8; kt2 += 2){
        STAGEF(kt2+1, smem + 20480); SB0;
        LOADAF(kt2+1, A1); SB0;
        PHASEF(A0, smem);
        BARN(4);
        if (kt2 + 2 < 8){
            STAGEF(kt2+2, smem); SB0;
            LOADAF(kt2+2, A0); SB0;
        }
        PHASEF(A1, smem + 20480);
        if (kt2 + 2 < 8) BARN(4);
    }
    BARE;   // all waves past B reads; smem becomes H1 [128][H1S] bf16 (per-wave private slabs)

    // ---- epilogue 1: + Am + Aa + PhiW, relu, bf16-pack -> H1
    #pragma unroll
    for (int rf = 0; rf < 2; rf++){
        int4 rc = rf ? rec1 : rec0;
        int pr = 32*w + 16*rf + l15;
        const unsigned char* amp = Am + (size_t)rc.x * HIDP;
        const unsigned char* aap = Aa + (size_t)rc.y * HIDP;
        int combo = (rc.z >> 19) & 0xFF;
        const unsigned short* php = PhiW + (size_t)combo * HIDP;
        char* h1row = smem + pr * (H1S*2);
        #pragma unroll
        for (int t = 0; t < 10; t++){
            int h0 = 16*t + 4*lh;
            unsigned int amd = *reinterpret_cast<const unsigned int*>(amp + h0);
            unsigned int aad = *reinterpret_cast<const unsigned int*>(aap + h0);
            ushort4 ph4 = *reinterpret_cast<const ushort4*>(php + h0);
            f32x2 amL = __builtin_amdgcn_cvt_pk_f32_fp8(amd, false);
            f32x2 amH = __builtin_amdgcn_cvt_pk_f32_fp8(amd, true);
            f32x2 aaL = __builtin_amdgcn_cvt_pk_f32_fp8(aad, false);
            f32x2 aaH = __builtin_amdgcn_cvt_pk_f32_fp8(aad, true);
            f32x4 a = acc1[t][rf];
            float v0 = fmaxf(a[0] + amL[0] + aaL[0] + bf2f(ph4.x), 0.f);
            float v1 = fmaxf(a[1] + amL[1] + aaL[1] + bf2f(ph4.y), 0.f);
            float v2 = fmaxf(a[2] + amH[0] + aaH[0] + bf2f(ph4.z), 0.f);
            float v3 = fmaxf(a[3] + amH[1] + aaH[1] + bf2f(ph4.w), 0.f);
            uint2 pk; pk.x = cvtpk(v0, v1); pk.y = cvtpk(v2, v3);
            *reinterpret_cast<uint2*>(h1row + h0*2) = pk;
        }
    }

    // ---- GEMM2: H2 = H1 @ W2 (H1 frags from own-wave LDS slab, W2 frags from global)
    f32x4 acc2[10][2];
    #pragma unroll
    for (int t = 0; t < 10; t++){ acc2[t][0] = (f32x4){0,0,0,0}; acc2[t][1] = (f32x4){0,0,0,0}; }
    const unsigned short* w2pb = W2T + (size_t)l15 * HIDP + lh * 8;
    #pragma unroll
    for (int k2 = 0; k2 < 5; k2++){
        bf16x8 h0f = *reinterpret_cast<const bf16x8*>(smem + (32*w + l15)      * (H1S*2) + k2*64 + lh*16);
        bf16x8 h1f = *reinterpret_cast<const bf16x8*>(smem + (32*w + 16 + l15) * (H1S*2) + k2*64 + lh*16);
        #pragma unroll
        for (int t = 0; t < 10; t++){
            bf16x8 wf = *reinterpret_cast<const bf16x8*>(w2pb + t * 16 * HIDP + k2 * 32);
            acc2[t][0] = __builtin_amdgcn_mfma_f32_16x16x32_bf16(wf, h0f, acc2[t][0], 0,0,0);
            acc2[t][1] = __builtin_amdgcn_mfma_f32_16x16x32_bf16(wf, h1f, acc2[t][1], 0,0,0);
        }
    }

    // ---- epilogue 2: relu(+b2), dot W3, + ms sum, scatter
    float b3v = b3[0];
    #pragma unroll
    for (int rf = 0; rf < 2; rf++){
        int4 rc = rf ? rec1 : rec0;
        float s = 0.f;
        #pragma unroll
        for (int t = 0; t < 10; t++){
            f32x4 w3v = *reinterpret_cast<const f32x4*>(w3p + 16*t + 4*lh);
            f32x4 b2v = *reinterpret_cast<const f32x4*>(b2p + 16*t + 4*lh);
            f32x4 a = acc2[t][rf];
            s += fmaxf(a[0] + b2v[0], 0.f) * w3v[0];
            s += fmaxf(a[1] + b2v[1], 0.f) * w3v[1];
            s += fmaxf(a[2] + b2v[2], 0.f) * w3v[2];
            s += fmaxf(a[3] + b2v[3], 0.f) * w3v[3];
        }
        s += __shfl_xor(s, 16);
        s += __shfl_xor(s, 32);
        if (!(rc.z & 0x80000000) && lh == 0){
            float val = s + b3v + __int_as_float(rc.w);
            dense[(size_t)((rc.z >> 5) & 0x3FFF) * KP1 + (rc.z & 31)] = val;
        }
    }
#undef STAGEF
#undef LOADAF
#undef PHASEF
}

// ---------------------------------------------------------------- phase 4: segment softmax
__global__ void k_softmax(const float* __restrict__ dense, const int* __restrict__ seg_lengths,
                          float* __restrict__ out, int S){
    int wid = threadIdx.x >> 6, lane = threadIdx.x & 63;
    int s = blockIdx.x * 4 + wid;
    if (s >= S) return;
    int len = seg_lengths[s];
    float ninf = -__builtin_inff();
    float val = ninf;
    if (lane < KP1) val = (lane < len) ? dense[(size_t)s * KP1 + lane] : ((lane == len) ? 0.f : ninf);
    float m = val;
    #pragma unroll
    for (int msk = 1; msk < 64; msk <<= 1) m = fmaxf(m, __shfl_xor(m, msk));
    float e = expf(val - m);
    float sum = e;
    #pragma unroll
    for (int msk = 1; msk < 64; msk <<= 1) sum += __shfl_xor(sum, msk);
    if (lane < KP1) out[(size_t)s * KP1 + lane] = (lane > len) ? 1000.f : (e / sum);
}

// ---------------------------------------------------------------- launch
extern "C" void kernel_launch(void* const* d_in, const int* in_sizes, int n_in,
                              void* d_out, int out_size, void* d_ws, size_t ws_size,
                              hipStream_t stream){
    const float* g_i        = (const float*)d_in[0];
    const float* ms         = (const float*)d_in[1];
    const float* dist_emb   = (const float*)d_in[2];
    const float* genre_emb  = (const float*)d_in[3];
    const float* spk_emb    = (const float*)d_in[4];
    const float* W1         = (const float*)d_in[5];
    const float* b1         = (const float*)d_in[6];
    const float* W2         = (const float*)d_in[7];
    const float* b2         = (const float*)d_in[8];
    const float* W3         = (const float*)d_in[9];
    const float* b3         = (const float*)d_in[10];
    const int* mention_ids  = (const int*)d_in[11];
    const int* antecedent_ids = (const int*)d_in[12];
    const int* dist_idx     = (const int*)d_in[13];
    const int* genre_idx    = (const int*)d_in[14];
    const int* spk_idx      = (const int*)d_in[15];
    const int* seg_ids      = (const int*)d_in[16];
    const int* pos_in_seg   = (const int*)d_in[17];
    const int* seg_lengths  = (const int*)d_in[18];
    int P = in_sizes[11];
    int S = in_sizes[18];

    char* ws = (char*)d_ws;
    unsigned short* W1tiles = (unsigned short*)(ws + 0);        // 3 x 163840 = 491520
    unsigned short* W2T     = (unsigned short*)(ws + 491520);   // 51200  -> 542720
    unsigned short* PhiW    = (unsigned short*)(ws + 542720);   // 67200  -> 609920
    float* w3pad            = (float*)(ws + 609920);            // 640    -> 610560
    float* b2pad            = (float*)(ws + 610560);            // 640    -> 611200
    unsigned char* g8       = (unsigned char*)(ws + 611200);    // 6144000  -> 6755200
    unsigned char* Am8      = (unsigned char*)(ws + 6755200);   // 1920000  -> 8675200
    unsigned char* Aa8      = (unsigned char*)(ws + 8675200);   // 1920000  -> 10595200
    int* hist               = (int*)(ws + 10595200);            // 48000    -> 10643200
    int* offsw              = (int*)(ws + 10643200);            // 48000    -> 10691200
    int4* recs              = (int4*)(ws + 10691200);           // (P+128)*16 -> < 13404800
    float* dense            = (float*)(ws + 13404800);          // 10001*31*4

    // prep (zero+sentinels+g8+W1tiles), weights, sort
    k_prep0<<<1500, 256, 0, stream>>>(g_i, g8, hist, recs, W1, W1tiles, P);
    k_wprep<<<211, 256, 0, stream>>>(dist_emb, genre_emb, spk_emb, W1, b1, W2, W3, b2,
                                     PhiW, W2T, w3pad, b2pad);
    k_hist<<<(P + 255)/256, 256, 0, stream>>>(mention_ids, hist, P);
    k_scan<<<1, 1024, 0, stream>>>(hist, offsw, NROWS);
    k_scatter<<<(P + 255)/256, 256, 0, stream>>>(mention_ids, antecedent_ids, dist_idx, genre_idx,
        spk_idx, seg_ids, pos_in_seg, ms, offsw, recs, P);

    // row projections Am / Aa (fp8 out; y=1 slice writes Aa8 = Am8 + NROWS*HIDP)
    k_proj<<<dim3((NROWS + BM - 1)/BM, 2), 256, 0, stream>>>(g8, W1tiles, Am8);

    // fused pair scorer
    k_fused<<<(P + BM - 1)/BM, 256, 0, stream>>>(g8, W1tiles + 2*81920, W2T, PhiW,
        Am8, Aa8, w3pad, b2pad, b3, recs, dense);

    // segment softmax
    k_softmax<<<(S + 3)/4, 256, 0, stream>>>(dense, seg_lengths, (float*)d_out, S);
}

// Round 7
// 116.282 us; speedup vs baseline: 1.4679x; 1.2405x over previous
//
#include <hip/hip_runtime.h>
#include <stdint.h>

#define GDIM   512
#define HID    150
#define HIDP   160    // HID padded (fp8 row stride for Am/Aa)
#define NROWS  12000
#define KP1    31     // KMAX+1
#define BM     128    // pairs (or rows) per block

typedef __attribute__((ext_vector_type(4))) float f32x4;
typedef __attribute__((ext_vector_type(2))) float f32x2;
typedef long i64;

__device__ __forceinline__ unsigned short f2bf(float x){
    unsigned int u = __float_as_uint(x);
    return (unsigned short)((u + 0x7fffu + ((u >> 16) & 1u)) >> 16);
}
__device__ __forceinline__ float bf2f(unsigned short u){
    return __uint_as_float(((unsigned int)u) << 16);
}
__device__ __forceinline__ i64 u2l(uint2 v){ return __builtin_bit_cast(i64, v); }
__device__ __forceinline__ f32x4 mfma8(i64 a, i64 b, f32x4 c){
    return __builtin_amdgcn_mfma_f32_16x16x32_fp8_fp8(a, b, c, 0, 0, 0);
}
// fp8x8 elementwise product (f32 math) -> fp8x8
__device__ __forceinline__ uint2 f8mulpk(uint2 m, uint2 a){
    f32x2 m0 = __builtin_amdgcn_cvt_pk_f32_fp8(m.x, false);
    f32x2 m1 = __builtin_amdgcn_cvt_pk_f32_fp8(m.x, true);
    f32x2 m2 = __builtin_amdgcn_cvt_pk_f32_fp8(m.y, false);
    f32x2 m3 = __builtin_amdgcn_cvt_pk_f32_fp8(m.y, true);
    f32x2 a0 = __builtin_amdgcn_cvt_pk_f32_fp8(a.x, false);
    f32x2 a1 = __builtin_amdgcn_cvt_pk_f32_fp8(a.x, true);
    f32x2 a2 = __builtin_amdgcn_cvt_pk_f32_fp8(a.y, false);
    f32x2 a3 = __builtin_amdgcn_cvt_pk_f32_fp8(a.y, true);
    unsigned int r0 = 0, r1 = 0;
    r0 = __builtin_amdgcn_cvt_pk_fp8_f32(m0[0]*a0[0], m0[1]*a0[1], r0, false);
    r0 = __builtin_amdgcn_cvt_pk_fp8_f32(m1[0]*a1[0], m1[1]*a1[1], r0, true);
    r1 = __builtin_amdgcn_cvt_pk_fp8_f32(m2[0]*a2[0], m2[1]*a2[1], r1, false);
    r1 = __builtin_amdgcn_cvt_pk_fp8_f32(m3[0]*a3[0], m3[1]*a3[1], r1, true);
    return (uint2){r0, r1};
}
// async global->LDS, 16B per lane, linear dest (dst = base + lane*16)
__device__ __forceinline__ void glds16(const void* g, void* l){
    __builtin_amdgcn_global_load_lds(
        (const __attribute__((address_space(1))) unsigned int*)g,
        (__attribute__((address_space(3))) unsigned int*)l, 16, 0, 0);
}

// ---------------------------------------------------------------- prep0: hist zero, sentinels, g8 (permuted fp8), W1 fp8 swizzled tables, W2 fp8 padded
// g8 row tile layout: g8[row*512 + kt*64 + lh*16 + kh*8 + e] = fp8(g[row, kt*64 + kh*32 + lh*8 + e])
// W18 slice s: W18[s*81920 + n*512 + (gi^(n&7))*8 + e] = fp8(W1[(s*512+gi*8+e)*HID + n])
// W28 [160][168] fp8 padded to 27648: W28[n2*168 + k] = fp8(W2[k*HID + n2])
__global__ void k_prep0(const float* __restrict__ g, unsigned char* __restrict__ g8,
                        int* __restrict__ hist, int4* __restrict__ recs,
                        const float* __restrict__ W1, unsigned char* __restrict__ W18,
                        const float* __restrict__ W2, unsigned char* __restrict__ W28, int P){
    int i = blockIdx.x * blockDim.x + threadIdx.x;
    if (i < NROWS) hist[i] = 0;
    if (i < BM) recs[P + i] = (int4){0, 0, (int)0x80000000, 0};
    if (i < 30720){
        int s = i / 10240, r = i % 10240;
        int n = r >> 6, gi = r & 63;
        int gdst = gi ^ (n & 7);
        int k0 = s * 512 + gi * 8;
        float x[8];
        #pragma unroll
        for (int e = 0; e < 8; e++) x[e] = (n < HID) ? W1[(size_t)(k0 + e) * HID + n] : 0.f;
        unsigned int d0 = 0, d1 = 0;
        d0 = __builtin_amdgcn_cvt_pk_fp8_f32(x[0], x[1], d0, false);
        d0 = __builtin_amdgcn_cvt_pk_fp8_f32(x[2], x[3], d0, true);
        d1 = __builtin_amdgcn_cvt_pk_fp8_f32(x[4], x[5], d1, false);
        d1 = __builtin_amdgcn_cvt_pk_fp8_f32(x[6], x[7], d1, true);
        *reinterpret_cast<uint2*>(W18 + (size_t)s * 81920 + n * 512 + gdst * 8) = (uint2){d0, d1};
    }
    if (i < 6912){   // W28: 6912 dwords = 27648 B
        int n2 = i / 42, kd = (i % 42) * 4;
        float y[4];
        #pragma unroll
        for (int e = 0; e < 4; e++){
            int k = kd + e;
            y[e] = (n2 < HID && k < HID) ? W2[(size_t)k * HID + n2] : 0.f;
        }
        unsigned int d = 0;
        d = __builtin_amdgcn_cvt_pk_fp8_f32(y[0], y[1], d, false);
        d = __builtin_amdgcn_cvt_pk_fp8_f32(y[2], y[3], d, true);
        reinterpret_cast<unsigned int*>(W28)[i] = d;
    }
    if (i >= NROWS * 32) return;
    int lh = i & 3, kt = (i >> 2) & 7, row = i >> 5;
    const float* src = g + (size_t)row * 512 + kt * 64 + lh * 8;
    float4 x0 = *reinterpret_cast<const float4*>(src);
    float4 x1 = *reinterpret_cast<const float4*>(src + 4);
    float4 x2 = *reinterpret_cast<const float4*>(src + 32);
    float4 x3 = *reinterpret_cast<const float4*>(src + 36);
    uint4 o; unsigned int d;
    d = 0; d = __builtin_amdgcn_cvt_pk_fp8_f32(x0.x, x0.y, d, false);
    d = __builtin_amdgcn_cvt_pk_fp8_f32(x0.z, x0.w, d, true);  o.x = d;
    d = 0; d = __builtin_amdgcn_cvt_pk_fp8_f32(x1.x, x1.y, d, false);
    d = __builtin_amdgcn_cvt_pk_fp8_f32(x1.z, x1.w, d, true);  o.y = d;
    d = 0; d = __builtin_amdgcn_cvt_pk_fp8_f32(x2.x, x2.y, d, false);
    d = __builtin_amdgcn_cvt_pk_fp8_f32(x2.z, x2.w, d, true);  o.z = d;
    d = 0; d = __builtin_amdgcn_cvt_pk_fp8_f32(x3.x, x3.y, d, false);
    d = __builtin_amdgcn_cvt_pk_fp8_f32(x3.z, x3.w, d, true);  o.w = d;
    *reinterpret_cast<uint4*>(g8 + (size_t)row * 512 + kt * 64 + lh * 16) = o;
}

// ---------------------------------------------------------------- wprep: PhiW (bf16) + W3/b2 pads
__global__ void k_wprep(const float* __restrict__ de, const float* __restrict__ ge,
                        const float* __restrict__ se, const float* __restrict__ W1,
                        const float* __restrict__ b1,
                        const float* __restrict__ W3, const float* __restrict__ b2,
                        unsigned short* __restrict__ PhiW,
                        float* __restrict__ w3p, float* __restrict__ b2p){
    int c = blockIdx.x, tid = threadIdx.x;
    if (c < 210 && tid < HIDP){
        int si = c % 3, gi2 = (c / 3) % 7, di = c / 21;
        float acc = 0.f;
        if (tid < HID){
            acc = b1[tid];
            #pragma unroll
            for (int dd = 0; dd < 20; dd++) acc += de[di*20 + dd] * W1[(size_t)(1536 + dd) * HID + tid];
            #pragma unroll
            for (int dd = 0; dd < 20; dd++) acc += ge[gi2*20 + dd] * W1[(size_t)(1556 + dd) * HID + tid];
            #pragma unroll
            for (int dd = 0; dd < 20; dd++) acc += se[si*20 + dd] * W1[(size_t)(1576 + dd) * HID + tid];
        }
        PhiW[c * HIDP + tid] = f2bf(acc);
    }
    if (c == 210 && tid < HIDP){
        w3p[tid] = (tid < HID) ? W3[tid] : 0.f;
        b2p[tid] = (tid < HID) ? b2[tid] : 0.f;
    }
}

// ---------------------------------------------------------------- sort kernels
__global__ void k_hist(const int* __restrict__ mid, int* __restrict__ hist, int P){
    int p = blockIdx.x * blockDim.x + threadIdx.x;
    if (p < P) atomicAdd(&hist[mid[p]], 1);
}
__global__ void k_scan(const int* __restrict__ hist, int* __restrict__ offsw, int nb){
    __shared__ int part[1024];
    int t = threadIdx.x;
    int chunk = (nb + 1023) / 1024;
    int lo = t * chunk, hi = lo + chunk; if (hi > nb) hi = nb;
    int s = 0;
    for (int b = lo; b < hi; b++) s += hist[b];
    part[t] = s;
    __syncthreads();
    for (int d = 1; d < 1024; d <<= 1){
        int v = (t >= d) ? part[t - d] : 0;
        __syncthreads();
        part[t] += v;
        __syncthreads();
    }
    int run = part[t] - s;
    for (int b = lo; b < hi; b++){ offsw[b] = run; run += hist[b]; }
}
__global__ void k_scatter(const int* __restrict__ mident, const int* __restrict__ antid,
                          const int* __restrict__ di, const int* __restrict__ gi, const int* __restrict__ si,
                          const int* __restrict__ seg, const int* __restrict__ pos, const float* __restrict__ ms,
                          int* __restrict__ offsw, int4* __restrict__ recs, int P){
    int p = blockIdx.x * blockDim.x + threadIdx.x;
    if (p >= P) return;
    int m = mident[p], a = antid[p];
    int idx = atomicAdd(&offsw[m], 1);
    int combo = (di[p] * 7 + gi[p]) * 3 + si[p];
    int meta = (combo << 19) | (seg[p] << 5) | pos[p];
    int4 r; r.x = m; r.y = a; r.z = meta; r.w = __float_as_int(ms[m] + ms[a]);
    recs[idx] = r;
}

// ================================================================ phase 1: Am/Aa projections — static W LDS, barrier-free K-loop, fp8 MFMA
__global__ __launch_bounds__(256) void k_proj(const unsigned char* __restrict__ g8,
                                              const unsigned char* __restrict__ W18,
                                              unsigned char* __restrict__ out){
    __shared__ __align__(16) char smem[81920];
    const unsigned char* Wt = W18 + (size_t)blockIdx.y * 81920;
    unsigned char* outh = out + (size_t)blockIdx.y * NROWS * HIDP;
    int tid = threadIdx.x, lane = tid & 63, w = tid >> 6;
    int l15 = lane & 15, lh = lane >> 4;
    int swz8 = (l15 & 7) << 3;
    int row0 = blockIdx.x * BM;

    int r0 = row0 + 32*w + l15;       int r0c = (r0 < NROWS) ? r0 : NROWS - 1;
    int r1 = r0 + 16;                 int r1c = (r1 < NROWS) ? r1 : NROWS - 1;
    const unsigned char* gp0 = g8 + (size_t)r0c * GDIM + lh * 16;
    const unsigned char* gp1 = g8 + (size_t)r1c * GDIM + lh * 16;

    // stage 80KB W slice once: 80 chunks, 20 per wave
    #pragma unroll
    for (int i = 0; i < 20; i++){
        int c = w * 20 + i;
        glds16(Wt + c * 1024 + lane * 16, smem + c * 1024);
    }

    f32x4 acc1[10][2];
    #pragma unroll
    for (int t = 0; t < 10; t++){ acc1[t][0] = (f32x4){0,0,0,0}; acc1[t][1] = (f32x4){0,0,0,0}; }

    asm volatile("s_waitcnt vmcnt(0)" ::: "memory");
    __builtin_amdgcn_s_barrier();

    uint4 R0 = *reinterpret_cast<const uint4*>(gp0);
    uint4 R1 = *reinterpret_cast<const uint4*>(gp1);
    #pragma unroll
    for (int kt = 0; kt < 8; kt++){
        uint4 N0, N1;
        if (kt < 7){
            N0 = *reinterpret_cast<const uint4*>(gp0 + (kt+1)*64);
            N1 = *reinterpret_cast<const uint4*>(gp1 + (kt+1)*64);
        }
        i64 a00 = u2l((uint2){R0.x, R0.y}), a01 = u2l((uint2){R0.z, R0.w});
        i64 a10 = u2l((uint2){R1.x, R1.y}), a11 = u2l((uint2){R1.z, R1.w});
        #pragma unroll
        for (int t = 0; t < 10; t++){
            int rowb = (t*16 + l15) * 512;
            i64 b0 = *reinterpret_cast<const i64*>(&smem[rowb + ((kt*64 +  0 + lh*8) ^ swz8)]);
            i64 b1 = *reinterpret_cast<const i64*>(&smem[rowb + ((kt*64 + 32 + lh*8) ^ swz8)]);
            acc1[t][0] = mfma8(b0, a00, acc1[t][0]);
            acc1[t][1] = mfma8(b0, a10, acc1[t][1]);
            acc1[t][0] = mfma8(b1, a01, acc1[t][0]);
            acc1[t][1] = mfma8(b1, a11, acc1[t][1]);
        }
        R0 = N0; R1 = N1;
    }

    // epilogue: 4 consecutive h per lane -> fp8 dword stores
    #pragma unroll
    for (int rf = 0; rf < 2; rf++){
        int row = row0 + 32*w + 16*rf + l15;
        if (row < NROWS){
            #pragma unroll
            for (int t = 0; t < 10; t++){
                f32x4 a = acc1[t][rf];
                unsigned int dw = 0;
                dw = __builtin_amdgcn_cvt_pk_fp8_f32(a[0], a[1], dw, false);
                dw = __builtin_amdgcn_cvt_pk_fp8_f32(a[2], a[3], dw, true);
                *reinterpret_cast<unsigned int*>(outh + (size_t)row * HIDP + 16*t + 4*lh) = dw;
            }
        }
    }
}

// ================================================================ fused pair scorer — static W LDS, barrier-free K-loop, fp8 end-to-end
__global__ __launch_bounds__(256) void k_fused(
    const unsigned char* __restrict__ g8,
    const unsigned char* __restrict__ W1c8, const unsigned char* __restrict__ W28,
    const unsigned short* __restrict__ PhiW, const unsigned char* __restrict__ Am,
    const unsigned char* __restrict__ Aa,
    const float* __restrict__ w3p, const float* __restrict__ b2p, const float* __restrict__ b3,
    const int4* __restrict__ recs,
    float* __restrict__ dense)
{
    __shared__ __align__(16) char smem[81920];   // W1c [160][512] fp8; later H1 [0,21504) + W2 [21504,49152)
    int tid = threadIdx.x, lane = tid & 63, w = tid >> 6;
    int l15 = lane & 15, lh = lane >> 4;
    int swz8 = (l15 & 7) << 3;
    int p0 = blockIdx.x * BM;

    int4 rec0 = recs[p0 + 32*w + l15];
    int4 rec1 = recs[p0 + 32*w + 16 + l15];

    const unsigned char* gm0 = g8 + (size_t)rec0.x * GDIM + lh * 16;
    const unsigned char* ga0 = g8 + (size_t)rec0.y * GDIM + lh * 16;
    const unsigned char* gm1 = g8 + (size_t)rec1.x * GDIM + lh * 16;
    const unsigned char* ga1 = g8 + (size_t)rec1.y * GDIM + lh * 16;

    // stage W1c (80KB) once: 80 chunks, 20/wave
    #pragma unroll
    for (int i = 0; i < 20; i++){
        int c = w * 20 + i;
        glds16(W1c8 + c * 1024 + lane * 16, smem + c * 1024);
    }

    f32x4 acc1[10][2];
    #pragma unroll
    for (int t = 0; t < 10; t++){ acc1[t][0] = (f32x4){0,0,0,0}; acc1[t][1] = (f32x4){0,0,0,0}; }

    asm volatile("s_waitcnt vmcnt(0)" ::: "memory");
    __builtin_amdgcn_s_barrier();

    // ---- GEMM1: barrier-free K-loop, manual 1-deep A prefetch
    uint4 Rm0 = *reinterpret_cast<const uint4*>(gm0);
    uint4 Ra0 = *reinterpret_cast<const uint4*>(ga0);
    uint4 Rm1 = *reinterpret_cast<const uint4*>(gm1);
    uint4 Ra1 = *reinterpret_cast<const uint4*>(ga1);
    #pragma unroll
    for (int kt = 0; kt < 8; kt++){
        uint4 Nm0, Na0, Nm1, Na1;
        if (kt < 7){
            Nm0 = *reinterpret_cast<const uint4*>(gm0 + (kt+1)*64);
            Na0 = *reinterpret_cast<const uint4*>(ga0 + (kt+1)*64);
            Nm1 = *reinterpret_cast<const uint4*>(gm1 + (kt+1)*64);
            Na1 = *reinterpret_cast<const uint4*>(ga1 + (kt+1)*64);
        }
        uint2 p00 = f8mulpk((uint2){Rm0.x, Rm0.y}, (uint2){Ra0.x, Ra0.y});
        uint2 p01 = f8mulpk((uint2){Rm0.z, Rm0.w}, (uint2){Ra0.z, Ra0.w});
        uint2 p10 = f8mulpk((uint2){Rm1.x, Rm1.y}, (uint2){Ra1.x, Ra1.y});
        uint2 p11 = f8mulpk((uint2){Rm1.z, Rm1.w}, (uint2){Ra1.z, Ra1.w});
        i64 lp00 = u2l(p00), lp01 = u2l(p01), lp10 = u2l(p10), lp11 = u2l(p11);
        #pragma unroll
        for (int t = 0; t < 10; t++){
            int rowb = (t*16 + l15) * 512;
            i64 b0 = *reinterpret_cast<const i64*>(&smem[rowb + ((kt*64 +  0 + lh*8) ^ swz8)]);
            i64 b1 = *reinterpret_cast<const i64*>(&smem[rowb + ((kt*64 + 32 + lh*8) ^ swz8)]);
            acc1[t][0] = mfma8(b0, lp00, acc1[t][0]);
            acc1[t][1] = mfma8(b0, lp10, acc1[t][1]);
            acc1[t][0] = mfma8(b1, lp01, acc1[t][0]);
            acc1[t][1] = mfma8(b1, lp11, acc1[t][1]);
        }
        Rm0 = Nm0; Ra0 = Na0; Rm1 = Nm1; Ra1 = Na1;
    }

    // all waves done reading W1c
    asm volatile("s_waitcnt lgkmcnt(0)" ::: "memory");
    __builtin_amdgcn_s_barrier();

    // stage W2 fp8 (27648B = 27 chunks) into [21504, 49152)
    #pragma unroll
    for (int i = 0; i < 7; i++){
        int c = w * 7 + i;
        if (c < 27) glds16(W28 + c * 1024 + lane * 16, smem + 21504 + c * 1024);
    }

    // ---- epilogue 1: + Am + Aa + PhiW, relu, fp8-pack -> H1 (own-wave slab, stride 168)
    #pragma unroll
    for (int rf = 0; rf < 2; rf++){
        int4 rc = rf ? rec1 : rec0;
        int pr = 32*w + 16*rf + l15;
        const unsigned char* amp = Am + (size_t)rc.x * HIDP;
        const unsigned char* aap = Aa + (size_t)rc.y * HIDP;
        int combo = (rc.z >> 19) & 0xFF;
        const unsigned short* php = PhiW + (size_t)combo * HIDP;
        char* h1row = smem + pr * 168;
        #pragma unroll
        for (int t = 0; t < 10; t++){
            int h0 = 16*t + 4*lh;
            unsigned int amd = *reinterpret_cast<const unsigned int*>(amp + h0);
            unsigned int aad = *reinterpret_cast<const unsigned int*>(aap + h0);
            ushort4 ph4 = *reinterpret_cast<const ushort4*>(php + h0);
            f32x2 amL = __builtin_amdgcn_cvt_pk_f32_fp8(amd, false);
            f32x2 amH = __builtin_amdgcn_cvt_pk_f32_fp8(amd, true);
            f32x2 aaL = __builtin_amdgcn_cvt_pk_f32_fp8(aad, false);
            f32x2 aaH = __builtin_amdgcn_cvt_pk_f32_fp8(aad, true);
            f32x4 a = acc1[t][rf];
            float v0 = fmaxf(a[0] + amL[0] + aaL[0] + bf2f(ph4.x), 0.f);
            float v1 = fmaxf(a[1] + amL[1] + aaL[1] + bf2f(ph4.y), 0.f);
            float v2 = fmaxf(a[2] + amH[0] + aaH[0] + bf2f(ph4.z), 0.f);
            float v3 = fmaxf(a[3] + amH[1] + aaH[1] + bf2f(ph4.w), 0.f);
            unsigned int dw = 0;
            dw = __builtin_amdgcn_cvt_pk_fp8_f32(v0, v1, dw, false);
            dw = __builtin_amdgcn_cvt_pk_fp8_f32(v2, v3, dw, true);
            *reinterpret_cast<unsigned int*>(h1row + h0) = dw;
        }
    }

    // W2 staged by all waves + own H1 written
    asm volatile("s_waitcnt vmcnt(0) lgkmcnt(0)" ::: "memory");
    __builtin_amdgcn_s_barrier();

    // ---- GEMM2: H2 = W2(LDS) x H1(LDS), fp8 MFMA
    f32x4 acc2[10][2];
    #pragma unroll
    for (int t = 0; t < 10; t++){ acc2[t][0] = (f32x4){0,0,0,0}; acc2[t][1] = (f32x4){0,0,0,0}; }
    const char* w2b = smem + 21504;
    #pragma unroll
    for (int k2 = 0; k2 < 5; k2++){
        i64 h0f = *reinterpret_cast<const i64*>(smem + (32*w + l15)      * 168 + k2*32 + lh*8);
        i64 h1f = *reinterpret_cast<const i64*>(smem + (32*w + 16 + l15) * 168 + k2*32 + lh*8);
        #pragma unroll
        for (int t = 0; t < 10; t++){
            i64 wf = *reinterpret_cast<const i64*>(w2b + (16*t + l15) * 168 + k2*32 + lh*8);
            acc2[t][0] = mfma8(wf, h0f, acc2[t][0]);
            acc2[t][1] = mfma8(wf, h1f, acc2[t][1]);
        }
    }

    // ---- epilogue 2: relu(+b2), dot W3, + ms sum, scatter
    float b3v = b3[0];
    #pragma unroll
    for (int rf = 0; rf < 2; rf++){
        int4 rc = rf ? rec1 : rec0;
        float s = 0.f;
        #pragma unroll
        for (int t = 0; t < 10; t++){
            f32x4 w3v = *reinterpret_cast<const f32x4*>(w3p + 16*t + 4*lh);
            f32x4 b2v = *reinterpret_cast<const f32x4*>(b2p + 16*t + 4*lh);
            f32x4 a = acc2[t][rf];
            s += fmaxf(a[0] + b2v[0], 0.f) * w3v[0];
            s += fmaxf(a[1] + b2v[1], 0.f) * w3v[1];
            s += fmaxf(a[2] + b2v[2], 0.f) * w3v[2];
            s += fmaxf(a[3] + b2v[3], 0.f) * w3v[3];
        }
        s += __shfl_xor(s, 16);
        s += __shfl_xor(s, 32);
        if (!(rc.z & 0x80000000) && lh == 0){
            float val = s + b3v + __int_as_float(rc.w);
            dense[(size_t)((rc.z >> 5) & 0x3FFF) * KP1 + (rc.z & 31)] = val;
        }
    }
}

// ---------------------------------------------------------------- phase 4: segment softmax
__global__ void k_softmax(const float* __restrict__ dense, const int* __restrict__ seg_lengths,
                          float* __restrict__ out, int S){
    int wid = threadIdx.x >> 6, lane = threadIdx.x & 63;
    int s = blockIdx.x * 4 + wid;
    if (s >= S) return;
    int len = seg_lengths[s];
    float ninf = -__builtin_inff();
    float val = ninf;
    if (lane < KP1) val = (lane < len) ? dense[(size_t)s * KP1 + lane] : ((lane == len) ? 0.f : ninf);
    float m = val;
    #pragma unroll
    for (int msk = 1; msk < 64; msk <<= 1) m = fmaxf(m, __shfl_xor(m, msk));
    float e = expf(val - m);
    float sum = e;
    #pragma unroll
    for (int msk = 1; msk < 64; msk <<= 1) sum += __shfl_xor(sum, msk);
    if (lane < KP1) out[(size_t)s * KP1 + lane] = (lane > len) ? 1000.f : (e / sum);
}

// ---------------------------------------------------------------- launch
extern "C" void kernel_launch(void* const* d_in, const int* in_sizes, int n_in,
                              void* d_out, int out_size, void* d_ws, size_t ws_size,
                              hipStream_t stream){
    const float* g_i        = (const float*)d_in[0];
    const float* ms         = (const float*)d_in[1];
    const float* dist_emb   = (const float*)d_in[2];
    const float* genre_emb  = (const float*)d_in[3];
    const float* spk_emb    = (const float*)d_in[4];
    const float* W1         = (const float*)d_in[5];
    const float* b1         = (const float*)d_in[6];
    const float* W2         = (const float*)d_in[7];
    const float* b2         = (const float*)d_in[8];
    const float* W3         = (const float*)d_in[9];
    const float* b3         = (const float*)d_in[10];
    const int* mention_ids  = (const int*)d_in[11];
    const int* antecedent_ids = (const int*)d_in[12];
    const int* dist_idx     = (const int*)d_in[13];
    const int* genre_idx    = (const int*)d_in[14];
    const int* spk_idx      = (const int*)d_in[15];
    const int* seg_ids      = (const int*)d_in[16];
    const int* pos_in_seg   = (const int*)d_in[17];
    const int* seg_lengths  = (const int*)d_in[18];
    int P = in_sizes[11];
    int S = in_sizes[18];

    char* ws = (char*)d_ws;
    unsigned char* W18   = (unsigned char*)(ws + 0);         // 3 x 81920 = 245760
    unsigned char* W28   = (unsigned char*)(ws + 245760);    // 27648   -> 273408
    unsigned short* PhiW = (unsigned short*)(ws + 273408);   // 67200   -> 340608
    float* w3pad         = (float*)(ws + 340608);            // 640     -> 341248
    float* b2pad         = (float*)(ws + 341248);            // 640     -> 341888
    unsigned char* g8    = (unsigned char*)(ws + 341888);    // 6144000 -> 6485888
    unsigned char* Am8   = (unsigned char*)(ws + 6485888);   // 1920000 -> 8405888
    unsigned char* Aa8   = (unsigned char*)(ws + 8405888);   // 1920000 -> 10325888
    int* hist            = (int*)(ws + 10325888);            // 48000   -> 10373888
    int* offsw           = (int*)(ws + 10373888);            // 48000   -> 10421888
    int4* recs           = (int4*)(ws + 10421888);           // (P+128)*16 -> <13000192
    float* dense         = (float*)(ws + 13000192);          // 10001*31*4

    k_prep0<<<1500, 256, 0, stream>>>(g_i, g8, hist, recs, W1, W18, W2, W28, P);
    k_wprep<<<211, 256, 0, stream>>>(dist_emb, genre_emb, spk_emb, W1, b1, W3, b2,
                                     PhiW, w3pad, b2pad);
    k_hist<<<(P + 255)/256, 256, 0, stream>>>(mention_ids, hist, P);
    k_scan<<<1, 1024, 0, stream>>>(hist, offsw, NROWS);
    k_scatter<<<(P + 255)/256, 256, 0, stream>>>(mention_ids, antecedent_ids, dist_idx, genre_idx,
        spk_idx, seg_ids, pos_in_seg, ms, offsw, recs, P);

    // row projections Am / Aa (fp8 out; y selects W1a/W1b slice and output half)
    k_proj<<<dim3((NROWS + BM - 1)/BM, 2), 256, 0, stream>>>(g8, W18, Am8);

    // fused pair scorer
    k_fused<<<(P + BM - 1)/BM, 256, 0, stream>>>(g8, W18 + 2*81920, W28, PhiW,
        Am8, Aa8, w3pad, b2pad, b3, recs, dense);

    // segment softmax
    k_softmax<<<(S + 3)/4, 256, 0, stream>>>(dense, seg_lengths, (float*)d_out, S);
}